// Round 5
// baseline (297.420 us; speedup 1.0000x reference)
//
#include <hip/hip_runtime.h>
#include <math.h>

// DTW 2048x2048, squared-diff cost, out = sqrt(DTW[2047][2047]).
//
// FULL ROW-STAGGER (anti-diagonal) wave pipeline, NW=4 waves (256 thr,
// 1 wave/SIMD), R=8 rows/lane. Lane l of wave w owns rows 512w+8l..+7;
// at wave-step t, row k is at column j_k = t - 8l - k (every row lags the
// row above by ONE column).
//
// WHY (rounds 0-4 evidence): the vertical-slice layout had an intra-step
// serial chain (8x min3+fma = 144cy/step, fully exposed at 1 wave/SIMD).
// R3 proved 2 waves/SIMD convoy (stalls coincide, no hiding); R1/R4 proved
// the compiler will NOT interleave two independent serial chains (it
// clusters each chain; per-step = sum). Fix: remove the intra-step chain
// from the DATAFLOW. With row-stagger 1, cell (k, j_k(t)) needs:
//   left = (k,   j_k-1) = c[k]   (end of step t-1)
//   up   = (k-1, j_k  ) = c[k-1] (end of step t-1)   [row k-1 is 1 col ahead]
//   diag = (k-1, j_k-1) = o[k-1] (end of step t-2)
// -> ALL 8 cells per step are independent; loop-carried chain = 1 cell
// (~10cy) << issue (~30 VALU x 2cy = 60cy). No scheduler ordering can
// serialize it. Cost: lane skew 8 -> intra-wave skew 511, DSKEW 576,
// GTOT 2496->4288 steps; model 4288x60cy = 108us vs 2496x144 = 150us.
//
// Conveyors (register-only, zero per-step LDS reads):
//   u = dpp_shr1(c7, ring[t]): lane l gets lane l-1's row-7 value from
//       step t-1 = (8l-1, t-8l) = up for row 0; uprev (u at t-1) = diag.
//       Lane 0 injects ring col t (row above the 512-row strip).
//   y: depth-8 register FIFO; head yn = dpp_shr1(y7, y[t]): lane l-1's
//       y7 (pre-shift) = y[(t-1)-8(l-1)-7] = y[t-8l] = lane l's head. Row
//       k>=1 uses y_{k-1} (pre-shift) = y[t-8l-k]. Shifts are SSA-renamed
//       (loop fully unrolled) -> zero movs.
//
// Ring (strip handoff, row 512w-1 values): lane l writes its row-7 value
// (col c = t-8l-7) every step -- stride 8/lane would be a 16-way bank
// conflict, so the ring uses a digit-swap layout:
//   idx(c') = (c'&7)*RSTR + (c'>>3),  c' = c + PAD
// Writes: c' = tau0+s+505-8l -> idx = [(s+1)&7]*RSTR + (s+505>>3)
//         + tau0/8 - l: stride-1 across lanes (conflict-free), compile-time
//         immediate per s. Block read (once/64 steps): lane l reads col
//         tau0+l at (l&7)*RSTR + tau0/8 + 64 + (l>>3) -- 4-way, negligible.
// Producer lane63 writes col c at step c+511; consumer block tau0 readlane-
// uses cols <= tau0+63; DSKEW=576 guarantees producer completed steps
// <= tau0+575 >= (tau0+63)+511 before the consumer's barrier. Last writer
// of col c is lane 63 (step c+511 > c+8l+7 for l<63) = the true boundary.
//
// Guard-free: INFV=1e30 absorbs adds (1e30+d^2==1e30 fp32); ramp junk
// (j<0) stays INFV; ramp-out junk (j>=2048, clamped y) is finite and only
// flows to larger j; OOB ring writes land in pads (PAD=512 covers c=-511).
// min3 via unsigned bitcast min (all values non-negative; IEEE order ==
// unsigned order) -> fuses to v_min3_u32.
//
// Output: row 2047 = w3/lane63/k=7 reaches col 2047 at t = 2047+511 = 2558
// = tau0 2496 (TAUMAX), s = 62.

#define NLEN   2048
#define NW     4
#define CSTEP  64
#define DSKEW  576
#define PAD    512
#define RSTR   386                      // perm sub-row stride (floats)
#define RROW   (8 * RSTR)               // 3088 floats per ring row
#define TAUMAX 2496
#define GTOT   (TAUMAX + CSTEP + (NW - 1) * DSKEW)   // 4288
#define INFV   1e30f

__device__ __forceinline__ float dpp_shr1(float v, float inj) {
    int r = __builtin_amdgcn_update_dpp(
        __builtin_bit_cast(int, inj), __builtin_bit_cast(int, v),
        0x138 /*wave_shr:1*/, 0xF, 0xF, false /*lane0 keeps old=inj*/);
    return __builtin_bit_cast(float, r);
}
__device__ __forceinline__ float rdlane(float v, int l) {
    return __builtin_bit_cast(float,
        __builtin_amdgcn_readlane(__builtin_bit_cast(int, v), l));
}
// 3-input min on non-negative floats via unsigned bit-pattern compare;
// umin+umin fuses to a single v_min3_u32.
__device__ __forceinline__ float min3f(float a, float b, float c) {
    unsigned ia = __builtin_bit_cast(unsigned, a);
    unsigned ib = __builtin_bit_cast(unsigned, b);
    unsigned ic = __builtin_bit_cast(unsigned, c);
    unsigned m  = __builtin_elementwise_min(
                      __builtin_elementwise_min(ia, ib), ic);
    return __builtin_bit_cast(float, m);
}

__global__ __launch_bounds__(256, 1) void dtw_kernel(const float* __restrict__ X,
                                                     const float* __restrict__ Y,
                                                     float* __restrict__ out) {
    __shared__ __align__(16) float yS[NLEN];
    __shared__ float ring[(NW + 1) * RROW];

    const int tid  = threadIdx.x;
    const int w    = tid >> 6;
    const int lane = tid & 63;

    {
        const float4* Y4 = (const float4*)Y;
        float4* y4 = (float4*)yS;
        y4[tid]       = Y4[tid];
        y4[tid + 256] = Y4[tid + 256];
    }
    // Entire ring INFV: virtual row -1, pads, and unwritten tails.
    for (int k = tid; k < (NW + 1) * RROW; k += 256) ring[k] = INFV;
    __syncthreads();

    float x0, x1, x2, x3, x4, x5, x6, x7;
    {
        const float4 xa = *(const float4*)&X[tid * 8];
        const float4 xb = *(const float4*)&X[tid * 8 + 4];
        x0 = xa.x; x1 = xa.y; x2 = xa.z; x3 = xa.w;
        x4 = xb.x; x5 = xb.y; x6 = xb.z; x7 = xb.w;
    }

    // c[k]: row k value at its current column (end of prev step).
    // o[k]: c[k] one step older (diag input for row k+1). o7 never needed.
    float c0 = INFV, c1 = INFV, c2 = INFV, c3 = INFV;
    float c4 = INFV, c5 = INFV, c6 = INFV, c7 = INFV;
    float o0 = INFV, o1 = INFV, o2 = INFV, o3 = INFV;
    float o4 = INFV, o5 = INFV, o6 = INFV;
    float y0 = 0.0f, y1 = 0.0f, y2 = 0.0f, y3 = 0.0f;
    float y4r = 0.0f, y5 = 0.0f, y6 = 0.0f, y7 = 0.0f;
    float uprev = (tid == 0) ? 0.0f : INFV;   // DTW[-1][-1]=0 seed

    const float* ringR = ring + w * RROW;
    float*       ringW = ring + (w + 1) * RROW;

    for (int gb = 0; gb < GTOT; gb += CSTEP) {
        const int tau0 = gb - w * DSKEW;

        if (tau0 >= 0 && tau0 <= TAUMAX) {
            int yi = tau0 + lane;                    // clamp for fake cols
            if (yi >= NLEN) yi = NLEN - 1;
            const float yblk = yS[yi];               // 1 coalesced ds_read
            // ring col tau0+lane via digit-swap layout (tau0 % 8 == 0):
            const float rblk = ringR[(lane & 7) * RSTR + (tau0 >> 3) + 64 + (lane >> 3)];
            // write base: idx(s) = [(s+1)&7]*RSTR + ((s+505)>>3) + tau0/8 - lane
            float* wbase = ringW + (tau0 >> 3) - lane;
            const bool isout = (tau0 == TAUMAX) & (w == NW - 1) & (lane == 63);

            #pragma unroll
            for (int s = 0; s < CSTEP; ++s) {
                const float yu = rdlane(yblk, s);    // y[tau0+s]
                const float ru = rdlane(rblk, s);    // ring col tau0+s
                const float yn = dpp_shr1(y7, yu);   // lane l: y[t-8l]
                const float u  = dpp_shr1(c7, ru);   // up for row 0
                // 8 INDEPENDENT cells (deps only on t-1 / t-2 state):
                float d0 = x0 - yn;  float n0 = fmaf(d0, d0, min3f(c0, u,  uprev));
                float d1 = x1 - y0;  float n1 = fmaf(d1, d1, min3f(c1, c0, o0));
                float d2 = x2 - y1;  float n2 = fmaf(d2, d2, min3f(c2, c1, o1));
                float d3 = x3 - y2;  float n3 = fmaf(d3, d3, min3f(c3, c2, o2));
                float d4 = x4 - y3;  float n4 = fmaf(d4, d4, min3f(c4, c3, o3));
                float d5 = x5 - y4r; float n5 = fmaf(d5, d5, min3f(c5, c4, o4));
                float d6 = x6 - y5;  float n6 = fmaf(d6, d6, min3f(c6, c5, o5));
                float d7 = x7 - y6;  float n7 = fmaf(d7, d7, min3f(c7, c6, o6));
                wbase[((s + 1) & 7) * RSTR + ((s + 505) >> 3)] = n7;
                // rotate state (SSA-renamed by the full unroll; zero movs)
                uprev = u;
                o0 = c0; o1 = c1; o2 = c2; o3 = c3; o4 = c4; o5 = c5; o6 = c6;
                c0 = n0; c1 = n1; c2 = n2; c3 = n3;
                c4 = n4; c5 = n5; c6 = n6; c7 = n7;
                y7 = y6; y6 = y5; y5 = y4r; y4r = y3;
                y3 = y2; y2 = y1; y1 = y0; y0 = yn;
                if (s == 62 && isout) out[0] = sqrtf(n7);  // j == 2047
            }
        }
        __syncthreads();
    }
}

extern "C" void kernel_launch(void* const* d_in, const int* in_sizes, int n_in,
                              void* d_out, int out_size, void* d_ws, size_t ws_size,
                              hipStream_t stream) {
    const float* x = (const float*)d_in[0];
    const float* y = (const float*)d_in[1];
    (void)in_sizes; (void)n_in; (void)out_size; (void)d_ws; (void)ws_size;
    dtw_kernel<<<1, 256, 0, stream>>>(x, y, (float*)d_out);
}

// Round 7
// 181.190 us; speedup vs baseline: 1.6415x; 1.6415x over previous
//
#include <hip/hip_runtime.h>
#include <math.h>

// DTW 2048x2048, squared-diff cost, out = sqrt(DTW[2047][2047]).
//
// TWO-COLUMNS-PER-STEP skew wave pipeline, NW=4 waves (256 thr,
// 1 wave/SIMD), R=8 rows/lane, vertical slices (no row stagger).
// Lane l of wave w owns rows 8*(64w+l)..+7; at wave-step s of block tau0
// it computes cols {tau0+2s-2l, tau0+2s+1-2l} (A,B) for all 8 rows.
//
// WHY (rounds 0-5 evidence): per-step time fits ~2.7cy x #ops + ~60cy
// fixed, INDEPENDENT of dependency structure (R0 31ops/144cy, R4 38/163,
// R5 chain-free 31/140; R3 showed 2 waves/SIMD convoy, R1/R4 showed the
// scheduler won't interleave independent chains). So the lever is CELLS
// PER STEP: 2 cols/step gives 16 cells for ~50 ops (vs 8 cells for 31)
// and halves the step count: 2496 -> 1376 steps (DSKEW grows 128->192
// for the 126-col lane lag). Model: 1376 x ~195cy = 112us vs 150us.
// Even if the scheduler serializes all 16 cells (R4 mode), ~210cy/step
// still wins -- the gain is structural, not scheduling-dependent.
//
// Op diet per step: 16 subs -> 8 v_pk_add_f32 (cols A,B of a row share
// x_k; (yA,yB) is a naturally-aligned register pair); y DPP conveyor
// DELETED -- each lane preloads its private 64-float y window into 32
// f32x2 regs per block (compile-time indexed, stays in VGPRs); u conveyor
// carries the (n7A,n7B) pair: 2 readlane + 2 DPP; ring write pairs into
// one ds_write_b64. min3/fma stay scalar (no packed f32 min3 exists).
//
// Dataflow per step (prev = previous step's value, all register-local):
//   row0: n0A = dA^2 + min3(pB0_prev, uA, uBp)     [left, up, diag]
//         n0B = dB^2 + min3(n0A, uB, uA)
//   rowk: nkA = dA^2 + min3(pBk_prev, n(k-1)A, pB(k-1)_prev)
//         nkB = dB^2 + min3(nkA, n(k-1)B, n(k-1)A)
//   uA = dpp_shr1(n7A_prev, ring[tau0+2s]);  uB = dpp_shr1(n7B_prev,
//   ring[tau0+2s+1]); uBp = uB_prev. Lane-0 injections = ring row above.
//
// Ring handoff proof: consumer block tau0 readlane-uses ring cols
// <= tau0+63. Producer (wave w-1, DSKEW=192 ahead) at the preceding
// barrier completed blocks through tau0+128; its lane63 (lag 126) wrote
// cols <= tau0+128+63-126 = tau0+65 >= tau0+63. Lane 63 is the last
// in-wave writer of every col (later program-order store wins).
//
// Guard-free correctness: all junk is LARGE in unsigned order (INFV=1e30,
// inf from d^2 overflow, NaN patterns) and min3 is unsigned-bitcast min,
// so junk absorbs at the first real col; junk cells (col<0 or >=2048)
// only flow rightward, never into output col 2047. y window reads are
// kept in-bounds by INFV pads around yS (junk y <=> junk col, exactly).
//
// Output: row 2047 = w3/lane63 row7, col 2047 = col B at tau0=2112
// (TAUMAX), s=30 (2112+61-126 = 2047).

#define NLEN   2048
#define NW     4
#define CSTEP  64                      // columns per block
#define SPB    (CSTEP / 2)             // 32 wave-steps per block
#define DSKEW  192
#define PAD    128
#define RROW   (PAD + 2176)            // ring cols -128..2175 -> 2304 floats
#define YPAD   128
#define TAUMAX 2112
#define GTOT   (TAUMAX + (NW - 1) * DSKEW + CSTEP)   // 2752
#define INFV   1e30f

typedef float f32x2 __attribute__((ext_vector_type(2)));

__device__ __forceinline__ float dpp_shr1(float v, float inj) {
    int r = __builtin_amdgcn_update_dpp(
        __builtin_bit_cast(int, inj), __builtin_bit_cast(int, v),
        0x138 /*wave_shr:1*/, 0xF, 0xF, false /*lane0 keeps old=inj*/);
    return __builtin_bit_cast(float, r);
}
__device__ __forceinline__ float rdlane(float v, int l) {
    return __builtin_bit_cast(float,
        __builtin_amdgcn_readlane(__builtin_bit_cast(int, v), l));
}
// 3-input min on non-negative floats via unsigned bit-pattern compare;
// umin+umin fuses to a single v_min3_u32. NaN/inf/1e30 all sort LARGE.
__device__ __forceinline__ float min3f(float a, float b, float c) {
    unsigned ia = __builtin_bit_cast(unsigned, a);
    unsigned ib = __builtin_bit_cast(unsigned, b);
    unsigned ic = __builtin_bit_cast(unsigned, c);
    unsigned m  = __builtin_elementwise_min(
                      __builtin_elementwise_min(ia, ib), ic);
    return __builtin_bit_cast(float, m);
}

__global__ __launch_bounds__(256, 1) void dtw_kernel(const float* __restrict__ X,
                                                     const float* __restrict__ Y,
                                                     float* __restrict__ out) {
    __shared__ __align__(16) float yB[YPAD + NLEN + YPAD];
    __shared__ float ring[(NW + 1) * RROW];
    float* yS = yB + YPAD;

    const int tid  = threadIdx.x;
    const int w    = tid >> 6;
    const int lane = tid & 63;

    {   // Y into the middle (16B-aligned since YPAD=128), INFV pads
        const float4* Y4 = (const float4*)Y;
        float4* y4 = (float4*)(yB + YPAD);
        y4[tid]       = Y4[tid];
        y4[tid + 256] = Y4[tid + 256];
        if (tid < YPAD) {
            yB[tid]               = INFV;    // low pad
            yB[YPAD + NLEN + tid] = INFV;    // high pad
        }
    }
    // Entire ring INFV: virtual row -1, pads, and unwritten tails.
    for (int k = tid; k < (NW + 1) * RROW; k += 256) ring[k] = INFV;
    __syncthreads();

    f32x2 xx0, xx1, xx2, xx3, xx4, xx5, xx6, xx7;
    {
        const float4 xa = *(const float4*)&X[tid * 8];
        const float4 xb = *(const float4*)&X[tid * 8 + 4];
        xx0 = (f32x2){xa.x, xa.x}; xx1 = (f32x2){xa.y, xa.y};
        xx2 = (f32x2){xa.z, xa.z}; xx3 = (f32x2){xa.w, xa.w};
        xx4 = (f32x2){xb.x, xb.x}; xx5 = (f32x2){xb.y, xb.y};
        xx6 = (f32x2){xb.z, xb.z}; xx7 = (f32x2){xb.w, xb.w};
    }

    // pBk: row-k col-B value of the previous step. a7p: row-7 col-A prev.
    float pB0 = INFV, pB1 = INFV, pB2 = INFV, pB3 = INFV;
    float pB4 = INFV, pB5 = INFV, pB6 = INFV, pB7 = INFV;
    float a7p = INFV;
    float uBp = (tid == 0) ? 0.0f : INFV;   // DTW[-1][-1]=0 seed

    const float* ringR = ring + w * RROW + PAD;
    float*       ringW = ring + (w + 1) * RROW + PAD;

    for (int gb = 0; gb < GTOT; gb += CSTEP) {
        const int tau0 = gb - w * DSKEW;

        if (tau0 >= 0 && tau0 <= TAUMAX) {
            const float rblk = ringR[tau0 + lane];   // ring cols tau0..+63
            // private y window: cols tau0-2l .. tau0-2l+63 (in-bounds in yB)
            f32x2 y2[SPB];
            {
                const f32x2* yp = (const f32x2*)(yS + (tau0 - 2 * lane));
                #pragma unroll
                for (int k = 0; k < SPB; ++k) y2[k] = yp[k];
            }
            float* wp = ringW + (tau0 - 2 * lane);
            const bool isout = (tau0 == TAUMAX) & (w == NW - 1) & (lane == 63);

            #pragma unroll
            for (int s = 0; s < SPB; ++s) {
                const float riA = rdlane(rblk, 2 * s);      // ring[tau0+2s]
                const float riB = rdlane(rblk, 2 * s + 1);  // ring[tau0+2s+1]
                const float uA  = dpp_shr1(a7p, riA);       // up for col A
                const float uB  = dpp_shr1(pB7, riB);       // up for col B
                const f32x2 yv = y2[s];
                f32x2 d0 = xx0 - yv;   // v_pk_add_f32 (neg)
                float n0A = fmaf(d0.x, d0.x, min3f(pB0, uA,  uBp));
                float n0B = fmaf(d0.y, d0.y, min3f(n0A, uB,  uA));
                f32x2 d1 = xx1 - yv;
                float n1A = fmaf(d1.x, d1.x, min3f(pB1, n0A, pB0));
                float n1B = fmaf(d1.y, d1.y, min3f(n1A, n0B, n0A));
                f32x2 d2 = xx2 - yv;
                float n2A = fmaf(d2.x, d2.x, min3f(pB2, n1A, pB1));
                float n2B = fmaf(d2.y, d2.y, min3f(n2A, n1B, n1A));
                f32x2 d3 = xx3 - yv;
                float n3A = fmaf(d3.x, d3.x, min3f(pB3, n2A, pB2));
                float n3B = fmaf(d3.y, d3.y, min3f(n3A, n2B, n2A));
                f32x2 d4 = xx4 - yv;
                float n4A = fmaf(d4.x, d4.x, min3f(pB4, n3A, pB3));
                float n4B = fmaf(d4.y, d4.y, min3f(n4A, n3B, n3A));
                f32x2 d5 = xx5 - yv;
                float n5A = fmaf(d5.x, d5.x, min3f(pB5, n4A, pB4));
                float n5B = fmaf(d5.y, d5.y, min3f(n5A, n4B, n4A));
                f32x2 d6 = xx6 - yv;
                float n6A = fmaf(d6.x, d6.x, min3f(pB6, n5A, pB5));
                float n6B = fmaf(d6.y, d6.y, min3f(n6A, n5B, n5A));
                f32x2 d7 = xx7 - yv;
                float n7A = fmaf(d7.x, d7.x, min3f(pB7, n6A, pB6));
                float n7B = fmaf(d7.y, d7.y, min3f(n7A, n6B, n6A));
                f32x2 wv; wv.x = n7A; wv.y = n7B;
                *(f32x2*)(wp + 2 * s) = wv;                 // ds_write_b64
                uBp = uB; a7p = n7A;
                pB0 = n0B; pB1 = n1B; pB2 = n2B; pB3 = n3B;
                pB4 = n4B; pB5 = n5B; pB6 = n6B; pB7 = n7B;
                if (s == 30 && isout) out[0] = sqrtf(n7B);  // col 2047
            }
        }
        __syncthreads();
    }
}

extern "C" void kernel_launch(void* const* d_in, const int* in_sizes, int n_in,
                              void* d_out, int out_size, void* d_ws, size_t ws_size,
                              hipStream_t stream) {
    const float* x = (const float*)d_in[0];
    const float* y = (const float*)d_in[1];
    (void)in_sizes; (void)n_in; (void)out_size; (void)d_ws; (void)ws_size;
    dtw_kernel<<<1, 256, 0, stream>>>(x, y, (float*)d_out);
}